// Round 22
// baseline (136.601 us; speedup 1.0000x reference)
//
#include <hip/hip_runtime.h>
#include <hip/hip_bf16.h>

// Problem constants (B,N,C,H,D,K) = (4, 8192, 384, 12, 2, 32)
#define B_  4
#define N_  8192
#define C_  384
#define H_  12
#define K_  32
#define M_  256          // N/K members per cluster
#define BN_ (B_*N_)      // 32768 rows
#define QKVD 1152        // 3*C
#define VSTR 260         // Vt row stride in elems (520B)
#define LOG2E 1.4426950408889634f

// qkv slab layout: [bh][n][96] (q16|k16|v64 per head) -> per-(b,h) slab 1.5MB
// feat2 slab layout: [bh][n][64] -> per-(b,h) slab 1MB

typedef __attribute__((ext_vector_type(8)))  short  bf16x8;
typedef __attribute__((ext_vector_type(4)))  float  f32x4;
typedef __attribute__((ext_vector_type(16))) float  f32x16;
typedef __attribute__((ext_vector_type(4)))  ushort ushort4v;
typedef __attribute__((ext_vector_type(8)))  ushort ushort8v;

#define GLOBAL_AS __attribute__((address_space(1)))
#define LDS_AS    __attribute__((address_space(3)))

__device__ __forceinline__ void load_lds_16B(const ushort* g, ushort* l) {
    __builtin_amdgcn_global_load_lds((const GLOBAL_AS unsigned int*)g,
                                     (LDS_AS unsigned int*)l, 16, 0, 0);
}
__device__ __forceinline__ unsigned cvtpk_bf16(float lo, float hi) {
    unsigned r;
    asm("v_cvt_pk_bf16_f32 %0, %1, %2" : "=v"(r) : "v"(lo), "v"(hi));
    return r;
}
__device__ __forceinline__ float exp2_fast(float x) {
    float r;
    asm("v_exp_f32 %0, %1" : "=v"(r) : "v"(x));
    return r;
}
__device__ __forceinline__ float rcp_fast(float x) {
    float r;
    asm("v_rcp_f32 %0, %1" : "=v"(r) : "v"(x));
    return r;
}

// ---------------------------------------------------------------- fused prologue
// Sections by block range (each = proven standalone kernel body):
//   [0, CF)        feat f32->bf16 cast          (3,145,728 f32x4 granules)
//   [CF, CF+CW)    w_qkv + w_proj cast          (184,320 granules)
//   [CF+CW, +8)    posmax partials              (8 blocks, plain stores -> no memset)
#define CF_BLK 12288
#define CW_BLK 720
#define WQN 110592   // 3*C*C/4 granules
#define WPN 73728    // C*2C/4 granules
__global__ __launch_bounds__(256) void prologue_kernel(const float* __restrict__ pos,
                                                       const float* __restrict__ feat,
                                                       const float* __restrict__ wq,
                                                       const float* __restrict__ wp,
                                                       unsigned* __restrict__ pmax,
                                                       ushort* __restrict__ featb,
                                                       ushort* __restrict__ wqb,
                                                       ushort* __restrict__ wpb) {
    const int bid = blockIdx.x;
    if (bid < CF_BLK) {
        int i = bid * 256 + threadIdx.x;                   // < 3,145,728 exactly
        float4 a = reinterpret_cast<const float4*>(feat)[i];
        unsigned u01 = cvtpk_bf16(a.x, a.y), u23 = cvtpk_bf16(a.z, a.w);
        ushort4 o = { (ushort)(u01 & 0xffff), (ushort)(u01 >> 16),
                      (ushort)(u23 & 0xffff), (ushort)(u23 >> 16) };
        reinterpret_cast<ushort4*>(featb)[i] = o;
        return;
    }
    if (bid < CF_BLK + CW_BLK) {
        int i = (bid - CF_BLK) * 256 + threadIdx.x;
        if (i >= WQN + WPN) return;
        const float* src; ushort* dst; int j;
        if (i < WQN) { src = wq; dst = wqb; j = i; }
        else         { src = wp; dst = wpb; j = i - WQN; }
        float4 a = reinterpret_cast<const float4*>(src)[j];
        unsigned u01 = cvtpk_bf16(a.x, a.y), u23 = cvtpk_bf16(a.z, a.w);
        ushort4 o = { (ushort)(u01 & 0xffff), (ushort)(u01 >> 16),
                      (ushort)(u23 & 0xffff), (ushort)(u23 >> 16) };
        reinterpret_cast<ushort4*>(dst)[j] = o;
        return;
    }
    // ---- posmax partials (8 virtual blocks; plain stores, rewritten every call)
    {
        int vb = bid - CF_BLK - CW_BLK;                    // 0..7
        int tid = vb * 256 + threadIdx.x;
        float m0 = 0.f, m1 = 0.f;
        for (int i = tid; i < BN_; i += 8 * 256) {
            m0 = fmaxf(m0, pos[(size_t)i * 2 + 0]);
            m1 = fmaxf(m1, pos[(size_t)i * 2 + 1]);
        }
        #pragma unroll
        for (int off = 32; off; off >>= 1) {
            m0 = fmaxf(m0, __shfl_down(m0, off));
            m1 = fmaxf(m1, __shfl_down(m1, off));
        }
        __shared__ float s0[4], s1[4];
        int w = threadIdx.x >> 6;
        if ((threadIdx.x & 63) == 0) { s0[w] = m0; s1[w] = m1; }
        __syncthreads();
        if (threadIdx.x == 0) {
            for (int i = 1; i < 4; i++) { m0 = fmaxf(m0, s0[i]); m1 = fmaxf(m1, s1[i]); }
            pmax[2 * vb + 0] = __float_as_uint(m0);
            pmax[2 * vb + 1] = __float_as_uint(m1);
        }
    }
}

// ---------------------------------------------------------------- QKV GEMM (256x128, single-buffer)
// r17 structure + launch_bounds(512,4): requests 2 blocks/CU (16 waves) so one
// block's stage latency hides under the other's MFMA (m114 implicit overlap).
// Unified regs ~124 <= 128 budget -> no spill expected.
__global__ __launch_bounds__(512, 4) void gemm_qkv_s(const ushort* __restrict__ A,
                                                     const ushort* __restrict__ Bw,
                                                     const float* __restrict__ bias,
                                                     ushort* __restrict__ qkv) {
    constexpr int NB = QKVD / 128;            // 9 column blocks
    __shared__ ushort As[256 * 64];           // 32 KB
    __shared__ ushort Bs[128 * 64];           // 16 KB
    const int wgid = blockIdx.x;              // 8*16*9 = 1152
    const int xcd  = wgid & 7;
    const int loc  = wgid >> 3;               // [0, 144)
    const int bm = (xcd * 16 + loc / NB) * 256;
    const int bn = (loc % NB) * 128;
    const int t = threadIdx.x;
    const int l = t & 63;
    const int wid = t >> 6;                   // 0..7
    const int wr = wid >> 1, wc = wid & 1;    // 4x2 wave grid, wave = 64x64 out
    const int fr = l & 15, fq = l >> 4;

    f32x4 zero = {0.f, 0.f, 0.f, 0.f};
    f32x4 acc[4][4];
    #pragma unroll
    for (int m = 0; m < 4; m++)
        #pragma unroll
        for (int n = 0; n < 4; n++) acc[m][n] = zero;

    for (int k0 = 0; k0 < 384; k0 += 64) {
        #pragma unroll
        for (int i = 0; i < 4; i++) {             // A: 256x64
            int elem = (i * 512 + t) * 8;
            int row = elem >> 6, kk = elem & 63;
            int kks = kk ^ ((row & 7) << 3);
            load_lds_16B(A + (size_t)(bm + row) * 384 + k0 + kks, &As[elem]);
        }
        #pragma unroll
        for (int i = 0; i < 2; i++) {             // B: 128x64
            int elem = (i * 512 + t) * 8;
            int row = elem >> 6, kk = elem & 63;
            int kks = kk ^ ((row & 7) << 3);
            load_lds_16B(Bw + (size_t)(bn + row) * 384 + k0 + kks, &Bs[elem]);
        }
        __syncthreads();
        #pragma unroll
        for (int kk = 0; kk < 64; kk += 32) {
            bf16x8 af[4], bfr[4];
            #pragma unroll
            for (int m = 0; m < 4; m++) {
                int row = wr * 64 + m * 16 + fr;
                af[m] = *reinterpret_cast<const bf16x8*>(&As[row * 64 + ((kk + fq * 8) ^ ((row & 7) << 3))]);
            }
            #pragma unroll
            for (int n = 0; n < 4; n++) {
                int row = wc * 64 + n * 16 + fr;
                bfr[n] = *reinterpret_cast<const bf16x8*>(&Bs[row * 64 + ((kk + fq * 8) ^ ((row & 7) << 3))]);
            }
            #pragma unroll
            for (int m = 0; m < 4; m++)
                #pragma unroll
                for (int n = 0; n < 4; n++)
                    acc[m][n] = __builtin_amdgcn_mfma_f32_16x16x32_bf16(af[m], bfr[n], acc[m][n], 0, 0, 0);
        }
        __syncthreads();
    }
    // epilogue -> qkv slab [bh][n][96]; 256-row tile all in one batch (8192 % 256 == 0)
    const int bq = bm >> 13;          // batch
    const int nbase = bm & (N_ - 1);  // row within batch
    #pragma unroll
    for (int n = 0; n < 4; n++) {
        int col = bn + wc * 64 + n * 16 + fr;
        int hc = col / 96, cn = col % 96;
        float bc = bias[col];
        ushort* base = qkv + ((size_t)(bq * H_ + hc) * N_ + nbase) * 96 + cn;
        #pragma unroll
        for (int m = 0; m < 4; m++) {
            #pragma unroll
            for (int r = 0; r < 4; r++) {
                int rowoff = wr * 64 + m * 16 + fq * 4 + r;
                unsigned up = cvtpk_bf16(acc[m][n][r] + bc, 0.f);
                base[(size_t)rowoff * 96] = (ushort)(up & 0xffff);
            }
        }
    }
}

// ---------------------------------------------------------------- MFMA attention
// 1-D grid: id%8 = bh&7 -> all 32 kc-blocks of one bh on one XCD (L2-resident slabs).
// 256 threads = 4 waves; wave w owns queries [64w, 64w+64) in TWO 32-query passes.
// V pack via v_perm (r10/r11-proven byte-exact). C/D layout (32x32): col = lane&31,
// row = (r&3) + 8*(r>>2) + 4*(lane>>5).
__global__ __launch_bounds__(256, 2) void attn_kernel(const ushort* __restrict__ qkv,
                                                      const int* __restrict__ member_idx,
                                                      const float* __restrict__ pos,
                                                      const float* __restrict__ w_pos,
                                                      const unsigned* __restrict__ pmax_u,
                                                      ushort* __restrict__ feat2) {
    const int id = blockIdx.x;
    const int bh = (id >> 8) * 8 + (id & 7);
    const int kc = (id >> 3) & 31;
    const int b = bh / H_, h = bh % H_;
    __shared__ ushort Ks[M_ * 16];        // 8 KB  [member][16]
    __shared__ ushort Vt[64 * VSTR];      // 32.5 KB [channel][member], padded stride
    __shared__ float  SpA[M_];            // bias*log2e, crow-reordered
    __shared__ int    Idx[M_];
    __shared__ float  dinvS[M_];          // per-query 1/sum

    const int t  = threadIdx.x;
    const int w  = t >> 6, l = t & 63;
    const int hi = l >> 5, ln = l & 31;
    const int* mi = member_idx + (((size_t)b * H_ + h) * K_ + kc) * M_;
    const ushort* slab = qkv + (size_t)bh * N_ * 96;
    const size_t rowbase = (size_t)b * N_;
    const float scale2 = 0.17677669529663687f * LOG2E;  // (C/H)^-0.5 * log2(e)

    // ---- early issue: Q fragments for both passes (queries 64w+ln, 64w+32+ln)
    const int nq0 = mi[w * 64 + ln];
    const int nq1 = mi[w * 64 + 32 + ln];
    bf16x8 qf0 = *(const bf16x8*)(slab + (size_t)nq0 * 96 + hi * 8);
    bf16x8 qf1 = *(const bf16x8*)(slab + (size_t)nq1 * 96 + hi * 8);
    // ---- K stage via global_load_lds (2 iters over 256 threads; r6-proven map)
    #pragma unroll
    for (int it = 0; it < 2; it++) {
        int idx = it * 256 + t;
        int row = idx >> 1, half = idx & 1;
        int n = mi[row];
        load_lds_16B(slab + (size_t)n * 96 + 16 + half * 8, &Ks[idx * 8]);
    }
    // ---- V load + pack-transpose via v_perm (r6 map: u = t>>1, 2 cq halves)
    {
        int u = t >> 1, cqh = t & 1;
        int n0 = mi[2 * u], n1 = mi[2 * u + 1];
        #pragma unroll
        for (int qq = 0; qq < 2; qq++) {
            int cq = 2 * cqh + qq;
            const ushort* s0 = slab + (size_t)n0 * 96 + 32 + cq * 16;
            const ushort* s1 = slab + (size_t)n1 * 96 + 32 + cq * 16;
            union { ushort8v v; unsigned u4[4]; } v0a, v0b, v1a, v1b;
            v0a.v = *(const ushort8v*)s0;
            v0b.v = *(const ushort8v*)(s0 + 8);
            v1a.v = *(const ushort8v*)s1;
            v1b.v = *(const ushort8v*)(s1 + 8);
            #pragma unroll
            for (int iw = 0; iw < 4; iw++) {
                unsigned ea = __builtin_amdgcn_perm(v1a.u4[iw], v0a.u4[iw], 0x05040100u);
                unsigned oa = __builtin_amdgcn_perm(v1a.u4[iw], v0a.u4[iw], 0x07060302u);
                *(unsigned*)&Vt[(cq * 16 + 2 * iw)     * VSTR + 2 * u] = ea;
                *(unsigned*)&Vt[(cq * 16 + 2 * iw + 1) * VSTR + 2 * u] = oa;
                unsigned eb = __builtin_amdgcn_perm(v1b.u4[iw], v0b.u4[iw], 0x05040100u);
                unsigned ob = __builtin_amdgcn_perm(v1b.u4[iw], v0b.u4[iw], 0x07060302u);
                *(unsigned*)&Vt[(cq * 16 + 8 + 2 * iw)     * VSTR + 2 * u] = eb;
                *(unsigned*)&Vt[(cq * 16 + 8 + 2 * iw + 1) * VSTR + 2 * u] = ob;
            }
        }
    }
    // ---- bias + Idx (crow-reordered, r13-proven formula; pmax = max of 8 partials)
    {
        int n = mi[t];
        Idx[t] = n;
        float f0 = __uint_as_float(pmax_u[0]), f1 = __uint_as_float(pmax_u[1]);
        #pragma unroll
        for (int k = 1; k < 8; k++) {
            f0 = fmaxf(f0, __uint_as_float(pmax_u[2 * k + 0]));
            f1 = fmaxf(f1, __uint_as_float(pmax_u[2 * k + 1]));
        }
        float inv0 = rcp_fast(f0);
        float inv1 = rcp_fast(f1);
        float sp = pos[(rowbase + n) * 2 + 0] * inv0 * w_pos[h * 2 + 0]
                 + pos[(rowbase + n) * 2 + 1] * inv1 * w_pos[h * 2 + 1];
        int jj = t & 31, jt = t >> 5;
        int r  = (jj & 3) | ((jj >> 3) << 2);
        int hb = (jj >> 2) & 1;
        SpA[jt * 32 + hb * 16 + r] = sp * LOG2E;
    }
    __syncthreads();

    f32x16 zero16;
    #pragma unroll
    for (int i = 0; i < 16; i++) zero16[i] = 0.f;
    ushort* f2slab = feat2 + (size_t)bh * N_ * 64;

    #pragma unroll
    for (int p = 0; p < 2; p++) {
        const int qb = w * 64 + p * 32;
        const bf16x8 qf = p ? qf1 : qf0;

        // ---- QK^T: 8 j-tiles of 32x32 (r13 body)
        f32x16 sac[8];
        __builtin_amdgcn_s_setprio(1);
        #pragma unroll
        for (int jt = 0; jt < 8; jt++) {
            bf16x8 kf = *(const bf16x8*)&Ks[(32 * jt + ln) * 16 + hi * 8];
            sac[jt] = __builtin_amdgcn_mfma_f32_32x32x16_bf16(kf, qf, zero16, 0, 0, 0);
        }
        __builtin_amdgcn_s_setprio(0);

        // ---- softmax in log2 domain (r13 body)
        float mx = -3.0e38f;
        #pragma unroll
        for (int jt = 0; jt < 8; jt++) {
            f32x4 bia[4];
            #pragma unroll
            for (int q4 = 0; q4 < 4; q4++)
                bia[q4] = *(const f32x4*)&SpA[jt * 32 + hi * 16 + q4 * 4];
            #pragma unroll
            for (int r = 0; r < 16; r++)
                sac[jt][r] = fmaf(sac[jt][r], scale2, bia[r >> 2][r & 3]);
            #pragma unroll
            for (int r = 0; r < 16; r += 2)
                mx = fmaxf(mx, fmaxf(sac[jt][r], sac[jt][r + 1]));   // -> v_max3
        }
        mx = fmaxf(mx, __shfl_xor(mx, 32));
        float sum = 0.f;
        #pragma unroll
        for (int jt = 0; jt < 8; jt++)
            #pragma unroll
            for (int r = 0; r < 16; r++) {
                float pv = exp2_fast(sac[jt][r] - mx);
                sac[jt][r] = pv;
                sum += pv;
            }
        sum += __shfl_xor(sum, 32);
        float inv = rcp_fast(sum);
        if (hi == 0) dinvS[qb + ln] = inv;

        // ---- PV (r13 body)
        f32x16 oa0 = zero16, oa1 = zero16;
        __builtin_amdgcn_s_setprio(1);
        #pragma unroll
        for (int g = 0; g < 16; g++) {
            const int jt = g >> 1, hf = (g & 1) * 8;
            unsigned a0 = cvtpk_bf16(sac[jt][hf + 0], sac[jt][hf + 1]);
            unsigned a1 = cvtpk_bf16(sac[jt][hf + 2], sac[jt][hf + 3]);
            unsigned b0 = cvtpk_bf16(sac[jt][hf + 4], sac[jt][hf + 5]);
            unsigned b1 = cvtpk_bf16(sac[jt][hf + 6], sac[jt][hf + 7]);
            asm("v_permlane32_swap_b32 %0, %1" : "+v"(a0), "+v"(b0));
            asm("v_permlane32_swap_b32 %0, %1" : "+v"(a1), "+v"(b1));
            union { unsigned uu[4]; bf16x8 v; } pa;
            pa.uu[0] = a0; pa.uu[1] = a1; pa.uu[2] = b0; pa.uu[3] = b1;
            union { ushort4v hv[2]; bf16x8 v; } vf0, vf1;
            vf0.hv[0] = *(const ushort4v*)&Vt[ln * VSTR + g * 16 + hi * 8];
            vf0.hv[1] = *(const ushort4v*)&Vt[ln * VSTR + g * 16 + hi * 8 + 4];
            vf1.hv[0] = *(const ushort4v*)&Vt[(ln + 32) * VSTR + g * 16 + hi * 8];
            vf1.hv[1] = *(const ushort4v*)&Vt[(ln + 32) * VSTR + g * 16 + hi * 8 + 4];
            oa0 = __builtin_amdgcn_mfma_f32_32x32x16_bf16(pa.v, vf0.v, oa0, 0, 0, 0);
            oa1 = __builtin_amdgcn_mfma_f32_32x32x16_bf16(pa.v, vf1.v, oa1, 0, 0, 0);
        }
        __builtin_amdgcn_s_setprio(0);

        // ---- epilogue (r13 body): lane holds O[i=crow(r,hi)][c=ln(+32)]
        #pragma unroll
        for (int r = 0; r < 16; r++) {
            int crow = (r & 3) + 8 * (r >> 2) + 4 * hi;
            float dv = dinvS[qb + crow];
            int ni = Idx[qb + crow];
            unsigned up = cvtpk_bf16(oa0[r] * dv, oa1[r] * dv);
            ushort* dst = f2slab + (size_t)ni * 64 + ln;
            dst[0]  = (ushort)(up & 0xffff);
            dst[32] = (ushort)(up >> 16);
        }
    }
}

// ---------------------------------------------------------------- proj GEMM (256x128, single-buffer)
// Same structure + launch_bounds(512,4) for 2 blocks/CU co-residency.
__global__ __launch_bounds__(512, 4) void gemm_proj_s(const ushort* __restrict__ A,
                                                      const ushort* __restrict__ Bw,
                                                      const float* __restrict__ bias,
                                                      float* __restrict__ Cout) {
    constexpr int NB = C_ / 128;              // 3 column blocks
    __shared__ ushort As[256 * 64];           // 32 KB
    __shared__ ushort Bs[128 * 64];           // 16 KB
    const int wgid = blockIdx.x;              // 8*16*3 = 384
    const int xcd  = wgid & 7;
    const int loc  = wgid >> 3;               // [0, 48)
    const int bm = (xcd * 16 + loc / NB) * 256;
    const int bn = (loc % NB) * 128;
    const int t = threadIdx.x;
    const int l = t & 63;
    const int wid = t >> 6;
    const int wr = wid >> 1, wc = wid & 1;    // 4x2 wave grid
    const int fr = l & 15, fq = l >> 4;
    const int bq = bm >> 13;                  // batch
    const int nbase = bm & (N_ - 1);

    f32x4 zero = {0.f, 0.f, 0.f, 0.f};
    f32x4 acc[4][4];
    #pragma unroll
    for (int m = 0; m < 4; m++)
        #pragma unroll
        for (int n = 0; n < 4; n++) acc[m][n] = zero;

    for (int k0 = 0; k0 < 768; k0 += 64) {
        const ushort* Aslab = A + ((size_t)(bq * H_ + (k0 >> 6)) * N_ + nbase) * 64;
        #pragma unroll
        for (int i = 0; i < 4; i++) {             // A: 256x64
            int elem = (i * 512 + t) * 8;
            int row = elem >> 6, kk = elem & 63;
            int kks = kk ^ ((row & 7) << 3);
            load_lds_16B(Aslab + (size_t)row * 64 + kks, &As[elem]);
        }
        #pragma unroll
        for (int i = 0; i < 2; i++) {             // B: 128x64
            int elem = (i * 512 + t) * 8;
            int row = elem >> 6, kk = elem & 63;
            int kks = kk ^ ((row & 7) << 3);
            load_lds_16B(Bw + (size_t)(bn + row) * 768 + k0 + kks, &Bs[elem]);
        }
        __syncthreads();
        #pragma unroll
        for (int kk = 0; kk < 64; kk += 32) {
            bf16x8 af[4], bfr[4];
            #pragma unroll
            for (int m = 0; m < 4; m++) {
                int row = wr * 64 + m * 16 + fr;
                af[m] = *reinterpret_cast<const bf16x8*>(&As[row * 64 + ((kk + fq * 8) ^ ((row & 7) << 3))]);
            }
            #pragma unroll
            for (int n = 0; n < 4; n++) {
                int row = wc * 64 + n * 16 + fr;
                bfr[n] = *reinterpret_cast<const bf16x8*>(&Bs[row * 64 + ((kk + fq * 8) ^ ((row & 7) << 3))]);
            }
            #pragma unroll
            for (int m = 0; m < 4; m++)
                #pragma unroll
                for (int n = 0; n < 4; n++)
                    acc[m][n] = __builtin_amdgcn_mfma_f32_16x16x32_bf16(af[m], bfr[n], acc[m][n], 0, 0, 0);
        }
        __syncthreads();
    }
    #pragma unroll
    for (int n = 0; n < 4; n++) {
        int col = bn + wc * 64 + n * 16 + fr;
        float bc = bias[col];
        #pragma unroll
        for (int m = 0; m < 4; m++) {
            #pragma unroll
            for (int r = 0; r < 4; r++) {
                size_t row = bm + wr * 64 + m * 16 + fq * 4 + r;
                Cout[row * C_ + col] = acc[m][n][r] + bc;
            }
        }
    }
}

// ---------------------------------------------------------------- launch
extern "C" void kernel_launch(void* const* d_in, const int* in_sizes, int n_in,
                              void* d_out, int out_size, void* d_ws, size_t ws_size,
                              hipStream_t stream) {
    const float* pos    = (const float*)d_in[0];
    const float* feat   = (const float*)d_in[1];
    const int*   midx   = (const int*)  d_in[2];
    const float* w_qkv  = (const float*)d_in[3];
    const float* b_qkv  = (const float*)d_in[4];
    const float* w_pos  = (const float*)d_in[5];
    const float* b_pos  = (const float*)d_in[6];  (void)b_pos; // cancels in softmax
    const float* w_proj = (const float*)d_in[7];
    const float* b_proj = (const float*)d_in[8];
    float* out = (float*)d_out;

    // workspace (126.4 MB, r5-proven):
    // [pmax 16 slots | qkv 75.5MB | wproj 0.59MB | REGION: {featb 25.2 + wqkvb 0.88} -> feat2 50.3]
    char* ws = (char*)d_ws;
    unsigned* pmax  = (unsigned*)ws;
    ushort*   qkv   = (ushort*)(ws + 256);
    ushort*   wproj = (ushort*)(ws + 256 + 75497472);
    char*     region = ws + 256 + 75497472 + 589824;
    ushort*   featb = (ushort*)region;
    ushort*   wqkvb = (ushort*)(region + 25165824);
    ushort*   feat2 = (ushort*)region;   // overwrites featb/wqkvb after gemm_qkv_s

    // no memset: posmax partials are plain-stored (fully rewritten) every call
    prologue_kernel<<<CF_BLK + CW_BLK + 8, 256, 0, stream>>>(pos, feat, w_qkv, w_proj,
                                                             pmax, featb, wqkvb, wproj);
    gemm_qkv_s<<<8 * 16 * (QKVD / 128), 512, 0, stream>>>(featb, wqkvb, b_qkv, qkv);
    attn_kernel<<<6 * 256, 256, 0, stream>>>(qkv, midx, pos, w_pos, pmax, feat2);
    gemm_proj_s<<<8 * 16 * (C_ / 128), 512, 0, stream>>>(feat2, wproj, b_proj, out);
}

// Round 23
// 135.812 us; speedup vs baseline: 1.0058x; 1.0058x over previous
//
#include <hip/hip_runtime.h>
#include <hip/hip_bf16.h>

// Problem constants (B,N,C,H,D,K) = (4, 8192, 384, 12, 2, 32)
#define B_  4
#define N_  8192
#define C_  384
#define H_  12
#define K_  32
#define M_  256          // N/K members per cluster
#define BN_ (B_*N_)      // 32768 rows
#define QKVD 1152        // 3*C
#define VSTR 260         // Vt row stride in elems (520B)
#define LOG2E 1.4426950408889634f

// qkv slab layout: [bh][n][96] (q16|k16|v64 per head) -> per-(b,h) slab 1.5MB
// feat2 slab layout: [bh][n][64] -> per-(b,h) slab 1MB

typedef __attribute__((ext_vector_type(8)))  short  bf16x8;
typedef __attribute__((ext_vector_type(4)))  float  f32x4;
typedef __attribute__((ext_vector_type(16))) float  f32x16;
typedef __attribute__((ext_vector_type(4)))  ushort ushort4v;
typedef __attribute__((ext_vector_type(8)))  ushort ushort8v;

#define GLOBAL_AS __attribute__((address_space(1)))
#define LDS_AS    __attribute__((address_space(3)))

__device__ __forceinline__ void load_lds_16B(const ushort* g, ushort* l) {
    __builtin_amdgcn_global_load_lds((const GLOBAL_AS unsigned int*)g,
                                     (LDS_AS unsigned int*)l, 16, 0, 0);
}
__device__ __forceinline__ unsigned cvtpk_bf16(float lo, float hi) {
    unsigned r;
    asm("v_cvt_pk_bf16_f32 %0, %1, %2" : "=v"(r) : "v"(lo), "v"(hi));
    return r;
}
__device__ __forceinline__ float exp2_fast(float x) {
    float r;
    asm("v_exp_f32 %0, %1" : "=v"(r) : "v"(x));
    return r;
}
__device__ __forceinline__ float rcp_fast(float x) {
    float r;
    asm("v_rcp_f32 %0, %1" : "=v"(r) : "v"(x));
    return r;
}

// ---------------------------------------------------------------- fused prologue
// Sections by block range (each = proven standalone kernel body):
//   [0, CF)        feat f32->bf16 cast          (3,145,728 f32x4 granules)
//   [CF, CF+CW)    w_qkv + w_proj cast          (184,320 granules)
//   [CF+CW, +8)    posmax partials              (8 blocks, plain stores -> no memset)
#define CF_BLK 12288
#define CW_BLK 720
#define WQN 110592   // 3*C*C/4 granules
#define WPN 73728    // C*2C/4 granules
__global__ __launch_bounds__(256) void prologue_kernel(const float* __restrict__ pos,
                                                       const float* __restrict__ feat,
                                                       const float* __restrict__ wq,
                                                       const float* __restrict__ wp,
                                                       unsigned* __restrict__ pmax,
                                                       ushort* __restrict__ featb,
                                                       ushort* __restrict__ wqb,
                                                       ushort* __restrict__ wpb) {
    const int bid = blockIdx.x;
    if (bid < CF_BLK) {
        int i = bid * 256 + threadIdx.x;                   // < 3,145,728 exactly
        float4 a = reinterpret_cast<const float4*>(feat)[i];
        unsigned u01 = cvtpk_bf16(a.x, a.y), u23 = cvtpk_bf16(a.z, a.w);
        ushort4 o = { (ushort)(u01 & 0xffff), (ushort)(u01 >> 16),
                      (ushort)(u23 & 0xffff), (ushort)(u23 >> 16) };
        reinterpret_cast<ushort4*>(featb)[i] = o;
        return;
    }
    if (bid < CF_BLK + CW_BLK) {
        int i = (bid - CF_BLK) * 256 + threadIdx.x;
        if (i >= WQN + WPN) return;
        const float* src; ushort* dst; int j;
        if (i < WQN) { src = wq; dst = wqb; j = i; }
        else         { src = wp; dst = wpb; j = i - WQN; }
        float4 a = reinterpret_cast<const float4*>(src)[j];
        unsigned u01 = cvtpk_bf16(a.x, a.y), u23 = cvtpk_bf16(a.z, a.w);
        ushort4 o = { (ushort)(u01 & 0xffff), (ushort)(u01 >> 16),
                      (ushort)(u23 & 0xffff), (ushort)(u23 >> 16) };
        reinterpret_cast<ushort4*>(dst)[j] = o;
        return;
    }
    // ---- posmax partials (8 virtual blocks; plain stores, rewritten every call)
    {
        int vb = bid - CF_BLK - CW_BLK;                    // 0..7
        int tid = vb * 256 + threadIdx.x;
        float m0 = 0.f, m1 = 0.f;
        for (int i = tid; i < BN_; i += 8 * 256) {
            m0 = fmaxf(m0, pos[(size_t)i * 2 + 0]);
            m1 = fmaxf(m1, pos[(size_t)i * 2 + 1]);
        }
        #pragma unroll
        for (int off = 32; off; off >>= 1) {
            m0 = fmaxf(m0, __shfl_down(m0, off));
            m1 = fmaxf(m1, __shfl_down(m1, off));
        }
        __shared__ float s0[4], s1[4];
        int w = threadIdx.x >> 6;
        if ((threadIdx.x & 63) == 0) { s0[w] = m0; s1[w] = m1; }
        __syncthreads();
        if (threadIdx.x == 0) {
            for (int i = 1; i < 4; i++) { m0 = fmaxf(m0, s0[i]); m1 = fmaxf(m1, s1[i]); }
            pmax[2 * vb + 0] = __float_as_uint(m0);
            pmax[2 * vb + 1] = __float_as_uint(m1);
        }
    }
}

// ---------------------------------------------------------------- QKV GEMM (256x128, BK=32 dbuf)
// 8 waves (4x2). Double-buffered at BK=32: LDS = 2*(256+128)*32*2B = 48KB (same as
// single-buffer BK=64 -> occupancy preserved, unlike r18's 96KB). Prefetch of step
// t+1 issued before compute(t); one barrier/step drains prefetch + protects swap
// (r18-correctness-proven pattern). 12 steps x 128 MFMA.
__global__ __launch_bounds__(512, 4) void gemm_qkv_s(const ushort* __restrict__ A,
                                                     const ushort* __restrict__ Bw,
                                                     const float* __restrict__ bias,
                                                     ushort* __restrict__ qkv) {
    constexpr int NB = QKVD / 128;            // 9 column blocks
    __shared__ ushort As[2][256 * 32];        // 32 KB
    __shared__ ushort Bs[2][128 * 32];        // 16 KB
    const int wgid = blockIdx.x;              // 8*16*9 = 1152
    const int xcd  = wgid & 7;
    const int loc  = wgid >> 3;               // [0, 144)
    const int bm = (xcd * 16 + loc / NB) * 256;
    const int bn = (loc % NB) * 128;
    const int t = threadIdx.x;
    const int l = t & 63;
    const int wid = t >> 6;                   // 0..7
    const int wr = wid >> 1, wc = wid & 1;    // 4x2 wave grid, wave = 64x64 out
    const int fr = l & 15, fq = l >> 4;

    // stage one BK=32 tile pair: A 2 gll/thread, B 1 gll/thread
    auto stage = [&](int buf, int k0) {
        #pragma unroll
        for (int i = 0; i < 2; i++) {             // A: 256x32 (1024 granules)
            int elem = (i * 512 + t) * 8;
            int row = elem >> 5, kk = elem & 31;
            int kks = kk ^ ((row & 3) << 3);      // 32-wide swizzle: row bits 0..1
            load_lds_16B(A + (size_t)(bm + row) * 384 + k0 + kks, &As[buf][elem]);
        }
        {                                         // B: 128x32 (512 granules)
            int elem = t * 8;
            int row = elem >> 5, kk = elem & 31;
            int kks = kk ^ ((row & 3) << 3);
            load_lds_16B(Bw + (size_t)(bn + row) * 384 + k0 + kks, &Bs[buf][elem]);
        }
    };

    f32x4 zero = {0.f, 0.f, 0.f, 0.f};
    f32x4 acc[4][4];
    #pragma unroll
    for (int m = 0; m < 4; m++)
        #pragma unroll
        for (int n = 0; n < 4; n++) acc[m][n] = zero;

    stage(0, 0);
    __syncthreads();                              // buf0 ready
    int cur = 0;
    for (int ks = 0; ks < 12; ++ks) {
        if (ks < 11) stage(cur ^ 1, (ks + 1) * 32);  // prefetch next (in flight during compute)
        {
            bf16x8 af[4], bfr[4];
            #pragma unroll
            for (int m = 0; m < 4; m++) {
                int row = wr * 64 + m * 16 + fr;
                af[m] = *reinterpret_cast<const bf16x8*>(&As[cur][row * 32 + ((fq * 8) ^ ((row & 3) << 3))]);
            }
            #pragma unroll
            for (int n = 0; n < 4; n++) {
                int row = wc * 64 + n * 16 + fr;
                bfr[n] = *reinterpret_cast<const bf16x8*>(&Bs[cur][row * 32 + ((fq * 8) ^ ((row & 3) << 3))]);
            }
            #pragma unroll
            for (int m = 0; m < 4; m++)
                #pragma unroll
                for (int n = 0; n < 4; n++)
                    acc[m][n] = __builtin_amdgcn_mfma_f32_16x16x32_bf16(af[m], bfr[n], acc[m][n], 0, 0, 0);
        }
        __syncthreads();                          // drains prefetch + protects swap
        cur ^= 1;
    }
    // epilogue -> qkv slab [bh][n][96]; 256-row tile all in one batch (8192 % 256 == 0)
    const int bq = bm >> 13;          // batch
    const int nbase = bm & (N_ - 1);  // row within batch
    #pragma unroll
    for (int n = 0; n < 4; n++) {
        int col = bn + wc * 64 + n * 16 + fr;
        int hc = col / 96, cn = col % 96;
        float bc = bias[col];
        ushort* base = qkv + ((size_t)(bq * H_ + hc) * N_ + nbase) * 96 + cn;
        #pragma unroll
        for (int m = 0; m < 4; m++) {
            #pragma unroll
            for (int r = 0; r < 4; r++) {
                int rowoff = wr * 64 + m * 16 + fq * 4 + r;
                unsigned up = cvtpk_bf16(acc[m][n][r] + bc, 0.f);
                base[(size_t)rowoff * 96] = (ushort)(up & 0xffff);
            }
        }
    }
}

// ---------------------------------------------------------------- MFMA attention
// 1-D grid: id%8 = bh&7 -> all 32 kc-blocks of one bh on one XCD (L2-resident slabs).
// 256 threads = 4 waves; wave w owns queries [64w, 64w+64) in TWO 32-query passes.
// V pack via v_perm (r10/r11-proven byte-exact). C/D layout (32x32): col = lane&31,
// row = (r&3) + 8*(r>>2) + 4*(lane>>5).
__global__ __launch_bounds__(256, 2) void attn_kernel(const ushort* __restrict__ qkv,
                                                      const int* __restrict__ member_idx,
                                                      const float* __restrict__ pos,
                                                      const float* __restrict__ w_pos,
                                                      const unsigned* __restrict__ pmax_u,
                                                      ushort* __restrict__ feat2) {
    const int id = blockIdx.x;
    const int bh = (id >> 8) * 8 + (id & 7);
    const int kc = (id >> 3) & 31;
    const int b = bh / H_, h = bh % H_;
    __shared__ ushort Ks[M_ * 16];        // 8 KB  [member][16]
    __shared__ ushort Vt[64 * VSTR];      // 32.5 KB [channel][member], padded stride
    __shared__ float  SpA[M_];            // bias*log2e, crow-reordered
    __shared__ int    Idx[M_];
    __shared__ float  dinvS[M_];          // per-query 1/sum

    const int t  = threadIdx.x;
    const int w  = t >> 6, l = t & 63;
    const int hi = l >> 5, ln = l & 31;
    const int* mi = member_idx + (((size_t)b * H_ + h) * K_ + kc) * M_;
    const ushort* slab = qkv + (size_t)bh * N_ * 96;
    const size_t rowbase = (size_t)b * N_;
    const float scale2 = 0.17677669529663687f * LOG2E;  // (C/H)^-0.5 * log2(e)

    // ---- early issue: Q fragments for both passes (queries 64w+ln, 64w+32+ln)
    const int nq0 = mi[w * 64 + ln];
    const int nq1 = mi[w * 64 + 32 + ln];
    bf16x8 qf0 = *(const bf16x8*)(slab + (size_t)nq0 * 96 + hi * 8);
    bf16x8 qf1 = *(const bf16x8*)(slab + (size_t)nq1 * 96 + hi * 8);
    // ---- K stage via global_load_lds (2 iters over 256 threads; r6-proven map)
    #pragma unroll
    for (int it = 0; it < 2; it++) {
        int idx = it * 256 + t;
        int row = idx >> 1, half = idx & 1;
        int n = mi[row];
        load_lds_16B(slab + (size_t)n * 96 + 16 + half * 8, &Ks[idx * 8]);
    }
    // ---- V load + pack-transpose via v_perm (r6 map: u = t>>1, 2 cq halves)
    {
        int u = t >> 1, cqh = t & 1;
        int n0 = mi[2 * u], n1 = mi[2 * u + 1];
        #pragma unroll
        for (int qq = 0; qq < 2; qq++) {
            int cq = 2 * cqh + qq;
            const ushort* s0 = slab + (size_t)n0 * 96 + 32 + cq * 16;
            const ushort* s1 = slab + (size_t)n1 * 96 + 32 + cq * 16;
            union { ushort8v v; unsigned u4[4]; } v0a, v0b, v1a, v1b;
            v0a.v = *(const ushort8v*)s0;
            v0b.v = *(const ushort8v*)(s0 + 8);
            v1a.v = *(const ushort8v*)s1;
            v1b.v = *(const ushort8v*)(s1 + 8);
            #pragma unroll
            for (int iw = 0; iw < 4; iw++) {
                unsigned ea = __builtin_amdgcn_perm(v1a.u4[iw], v0a.u4[iw], 0x05040100u);
                unsigned oa = __builtin_amdgcn_perm(v1a.u4[iw], v0a.u4[iw], 0x07060302u);
                *(unsigned*)&Vt[(cq * 16 + 2 * iw)     * VSTR + 2 * u] = ea;
                *(unsigned*)&Vt[(cq * 16 + 2 * iw + 1) * VSTR + 2 * u] = oa;
                unsigned eb = __builtin_amdgcn_perm(v1b.u4[iw], v0b.u4[iw], 0x05040100u);
                unsigned ob = __builtin_amdgcn_perm(v1b.u4[iw], v0b.u4[iw], 0x07060302u);
                *(unsigned*)&Vt[(cq * 16 + 8 + 2 * iw)     * VSTR + 2 * u] = eb;
                *(unsigned*)&Vt[(cq * 16 + 8 + 2 * iw + 1) * VSTR + 2 * u] = ob;
            }
        }
    }
    // ---- bias + Idx (crow-reordered, r13-proven formula; pmax = max of 8 partials)
    {
        int n = mi[t];
        Idx[t] = n;
        float f0 = __uint_as_float(pmax_u[0]), f1 = __uint_as_float(pmax_u[1]);
        #pragma unroll
        for (int k = 1; k < 8; k++) {
            f0 = fmaxf(f0, __uint_as_float(pmax_u[2 * k + 0]));
            f1 = fmaxf(f1, __uint_as_float(pmax_u[2 * k + 1]));
        }
        float inv0 = rcp_fast(f0);
        float inv1 = rcp_fast(f1);
        float sp = pos[(rowbase + n) * 2 + 0] * inv0 * w_pos[h * 2 + 0]
                 + pos[(rowbase + n) * 2 + 1] * inv1 * w_pos[h * 2 + 1];
        int jj = t & 31, jt = t >> 5;
        int r  = (jj & 3) | ((jj >> 3) << 2);
        int hb = (jj >> 2) & 1;
        SpA[jt * 32 + hb * 16 + r] = sp * LOG2E;
    }
    __syncthreads();

    f32x16 zero16;
    #pragma unroll
    for (int i = 0; i < 16; i++) zero16[i] = 0.f;
    ushort* f2slab = feat2 + (size_t)bh * N_ * 64;

    #pragma unroll
    for (int p = 0; p < 2; p++) {
        const int qb = w * 64 + p * 32;
        const bf16x8 qf = p ? qf1 : qf0;

        // ---- QK^T: 8 j-tiles of 32x32 (r13 body)
        f32x16 sac[8];
        __builtin_amdgcn_s_setprio(1);
        #pragma unroll
        for (int jt = 0; jt < 8; jt++) {
            bf16x8 kf = *(const bf16x8*)&Ks[(32 * jt + ln) * 16 + hi * 8];
            sac[jt] = __builtin_amdgcn_mfma_f32_32x32x16_bf16(kf, qf, zero16, 0, 0, 0);
        }
        __builtin_amdgcn_s_setprio(0);

        // ---- softmax in log2 domain (r13 body)
        float mx = -3.0e38f;
        #pragma unroll
        for (int jt = 0; jt < 8; jt++) {
            f32x4 bia[4];
            #pragma unroll
            for (int q4 = 0; q4 < 4; q4++)
                bia[q4] = *(const f32x4*)&SpA[jt * 32 + hi * 16 + q4 * 4];
            #pragma unroll
            for (int r = 0; r < 16; r++)
                sac[jt][r] = fmaf(sac[jt][r], scale2, bia[r >> 2][r & 3]);
            #pragma unroll
            for (int r = 0; r < 16; r += 2)
                mx = fmaxf(mx, fmaxf(sac[jt][r], sac[jt][r + 1]));   // -> v_max3
        }
        mx = fmaxf(mx, __shfl_xor(mx, 32));
        float sum = 0.f;
        #pragma unroll
        for (int jt = 0; jt < 8; jt++)
            #pragma unroll
            for (int r = 0; r < 16; r++) {
                float pv = exp2_fast(sac[jt][r] - mx);
                sac[jt][r] = pv;
                sum += pv;
            }
        sum += __shfl_xor(sum, 32);
        float inv = rcp_fast(sum);
        if (hi == 0) dinvS[qb + ln] = inv;

        // ---- PV (r13 body)
        f32x16 oa0 = zero16, oa1 = zero16;
        __builtin_amdgcn_s_setprio(1);
        #pragma unroll
        for (int g = 0; g < 16; g++) {
            const int jt = g >> 1, hf = (g & 1) * 8;
            unsigned a0 = cvtpk_bf16(sac[jt][hf + 0], sac[jt][hf + 1]);
            unsigned a1 = cvtpk_bf16(sac[jt][hf + 2], sac[jt][hf + 3]);
            unsigned b0 = cvtpk_bf16(sac[jt][hf + 4], sac[jt][hf + 5]);
            unsigned b1 = cvtpk_bf16(sac[jt][hf + 6], sac[jt][hf + 7]);
            asm("v_permlane32_swap_b32 %0, %1" : "+v"(a0), "+v"(b0));
            asm("v_permlane32_swap_b32 %0, %1" : "+v"(a1), "+v"(b1));
            union { unsigned uu[4]; bf16x8 v; } pa;
            pa.uu[0] = a0; pa.uu[1] = a1; pa.uu[2] = b0; pa.uu[3] = b1;
            union { ushort4v hv[2]; bf16x8 v; } vf0, vf1;
            vf0.hv[0] = *(const ushort4v*)&Vt[ln * VSTR + g * 16 + hi * 8];
            vf0.hv[1] = *(const ushort4v*)&Vt[ln * VSTR + g * 16 + hi * 8 + 4];
            vf1.hv[0] = *(const ushort4v*)&Vt[(ln + 32) * VSTR + g * 16 + hi * 8];
            vf1.hv[1] = *(const ushort4v*)&Vt[(ln + 32) * VSTR + g * 16 + hi * 8 + 4];
            oa0 = __builtin_amdgcn_mfma_f32_32x32x16_bf16(pa.v, vf0.v, oa0, 0, 0, 0);
            oa1 = __builtin_amdgcn_mfma_f32_32x32x16_bf16(pa.v, vf1.v, oa1, 0, 0, 0);
        }
        __builtin_amdgcn_s_setprio(0);

        // ---- epilogue (r13 body): lane holds O[i=crow(r,hi)][c=ln(+32)]
        #pragma unroll
        for (int r = 0; r < 16; r++) {
            int crow = (r & 3) + 8 * (r >> 2) + 4 * hi;
            float dv = dinvS[qb + crow];
            int ni = Idx[qb + crow];
            unsigned up = cvtpk_bf16(oa0[r] * dv, oa1[r] * dv);
            ushort* dst = f2slab + (size_t)ni * 64 + ln;
            dst[0]  = (ushort)(up & 0xffff);
            dst[32] = (ushort)(up >> 16);
        }
    }
}

// ---------------------------------------------------------------- proj GEMM (256x128, single-buffer)
// r20-proven structure + launch_bounds(512,4).
__global__ __launch_bounds__(512, 4) void gemm_proj_s(const ushort* __restrict__ A,
                                                      const ushort* __restrict__ Bw,
                                                      const float* __restrict__ bias,
                                                      float* __restrict__ Cout) {
    constexpr int NB = C_ / 128;              // 3 column blocks
    __shared__ ushort As[256 * 64];           // 32 KB
    __shared__ ushort Bs[128 * 64];           // 16 KB
    const int wgid = blockIdx.x;              // 8*16*3 = 384
    const int xcd  = wgid & 7;
    const int loc  = wgid >> 3;               // [0, 48)
    const int bm = (xcd * 16 + loc / NB) * 256;
    const int bn = (loc % NB) * 128;
    const int t = threadIdx.x;
    const int l = t & 63;
    const int wid = t >> 6;
    const int wr = wid >> 1, wc = wid & 1;    // 4x2 wave grid
    const int fr = l & 15, fq = l >> 4;
    const int bq = bm >> 13;                  // batch
    const int nbase = bm & (N_ - 1);

    f32x4 zero = {0.f, 0.f, 0.f, 0.f};
    f32x4 acc[4][4];
    #pragma unroll
    for (int m = 0; m < 4; m++)
        #pragma unroll
        for (int n = 0; n < 4; n++) acc[m][n] = zero;

    for (int k0 = 0; k0 < 768; k0 += 64) {
        const ushort* Aslab = A + ((size_t)(bq * H_ + (k0 >> 6)) * N_ + nbase) * 64;
        #pragma unroll
        for (int i = 0; i < 4; i++) {             // A: 256x64
            int elem = (i * 512 + t) * 8;
            int row = elem >> 6, kk = elem & 63;
            int kks = kk ^ ((row & 7) << 3);
            load_lds_16B(Aslab + (size_t)row * 64 + kks, &As[elem]);
        }
        #pragma unroll
        for (int i = 0; i < 2; i++) {             // B: 128x64
            int elem = (i * 512 + t) * 8;
            int row = elem >> 6, kk = elem & 63;
            int kks = kk ^ ((row & 7) << 3);
            load_lds_16B(Bw + (size_t)(bn + row) * 768 + k0 + kks, &Bs[elem]);
        }
        __syncthreads();
        #pragma unroll
        for (int kk = 0; kk < 64; kk += 32) {
            bf16x8 af[4], bfr[4];
            #pragma unroll
            for (int m = 0; m < 4; m++) {
                int row = wr * 64 + m * 16 + fr;
                af[m] = *reinterpret_cast<const bf16x8*>(&As[row * 64 + ((kk + fq * 8) ^ ((row & 7) << 3))]);
            }
            #pragma unroll
            for (int n = 0; n < 4; n++) {
                int row = wc * 64 + n * 16 + fr;
                bfr[n] = *reinterpret_cast<const bf16x8*>(&Bs[row * 64 + ((kk + fq * 8) ^ ((row & 7) << 3))]);
            }
            #pragma unroll
            for (int m = 0; m < 4; m++)
                #pragma unroll
                for (int n = 0; n < 4; n++)
                    acc[m][n] = __builtin_amdgcn_mfma_f32_16x16x32_bf16(af[m], bfr[n], acc[m][n], 0, 0, 0);
        }
        __syncthreads();
    }
    #pragma unroll
    for (int n = 0; n < 4; n++) {
        int col = bn + wc * 64 + n * 16 + fr;
        float bc = bias[col];
        #pragma unroll
        for (int m = 0; m < 4; m++) {
            #pragma unroll
            for (int r = 0; r < 4; r++) {
                size_t row = bm + wr * 64 + m * 16 + fq * 4 + r;
                Cout[row * C_ + col] = acc[m][n][r] + bc;
            }
        }
    }
}

// ---------------------------------------------------------------- launch
extern "C" void kernel_launch(void* const* d_in, const int* in_sizes, int n_in,
                              void* d_out, int out_size, void* d_ws, size_t ws_size,
                              hipStream_t stream) {
    const float* pos    = (const float*)d_in[0];
    const float* feat   = (const float*)d_in[1];
    const int*   midx   = (const int*)  d_in[2];
    const float* w_qkv  = (const float*)d_in[3];
    const float* b_qkv  = (const float*)d_in[4];
    const float* w_pos  = (const float*)d_in[5];
    const float* b_pos  = (const float*)d_in[6];  (void)b_pos; // cancels in softmax
    const float* w_proj = (const float*)d_in[7];
    const float* b_proj = (const float*)d_in[8];
    float* out = (float*)d_out;

    // workspace (126.4 MB, r5-proven):
    // [pmax 16 slots | qkv 75.5MB | wproj 0.59MB | REGION: {featb 25.2 + wqkvb 0.88} -> feat2 50.3]
    char* ws = (char*)d_ws;
    unsigned* pmax  = (unsigned*)ws;
    ushort*   qkv   = (ushort*)(ws + 256);
    ushort*   wproj = (ushort*)(ws + 256 + 75497472);
    char*     region = ws + 256 + 75497472 + 589824;
    ushort*   featb = (ushort*)region;
    ushort*   wqkvb = (ushort*)(region + 25165824);
    ushort*   feat2 = (ushort*)region;   // overwrites featb/wqkvb after gemm_qkv_s

    // no memset: posmax partials are plain-stored (fully rewritten) every call
    prologue_kernel<<<CF_BLK + CW_BLK + 8, 256, 0, stream>>>(pos, feat, w_qkv, w_proj,
                                                             pmax, featb, wqkvb, wproj);
    gemm_qkv_s<<<8 * 16 * (QKVD / 128), 512, 0, stream>>>(featb, wqkvb, b_qkv, qkv);
    attn_kernel<<<6 * 256, 256, 0, stream>>>(qkv, midx, pos, w_pos, pmax, feat2);
    gemm_proj_s<<<8 * 16 * (C_ / 128), 512, 0, stream>>>(feat2, wproj, b_proj, out);
}

// Round 24
// 132.608 us; speedup vs baseline: 1.0301x; 1.0242x over previous
//
#include <hip/hip_runtime.h>
#include <hip/hip_bf16.h>

// Problem constants (B,N,C,H,D,K) = (4, 8192, 384, 12, 2, 32)
#define B_  4
#define N_  8192
#define C_  384
#define H_  12
#define K_  32
#define M_  256          // N/K members per cluster
#define BN_ (B_*N_)      // 32768 rows
#define QKVD 1152        // 3*C
#define VSTR 260         // Vt row stride in elems (520B)
#define LOG2E 1.4426950408889634f

// qkv slab layout: [bh][n][96] (q16|k16|v64 per head) -> per-(b,h) slab 1.5MB
// feat2 slab layout: [bh][n][64] -> per-(b,h) slab 1MB

typedef __attribute__((ext_vector_type(8)))  short  bf16x8;
typedef __attribute__((ext_vector_type(4)))  float  f32x4;
typedef __attribute__((ext_vector_type(16))) float  f32x16;
typedef __attribute__((ext_vector_type(4)))  ushort ushort4v;
typedef __attribute__((ext_vector_type(8)))  ushort ushort8v;

#define GLOBAL_AS __attribute__((address_space(1)))
#define LDS_AS    __attribute__((address_space(3)))

__device__ __forceinline__ void load_lds_16B(const ushort* g, ushort* l) {
    __builtin_amdgcn_global_load_lds((const GLOBAL_AS unsigned int*)g,
                                     (LDS_AS unsigned int*)l, 16, 0, 0);
}
__device__ __forceinline__ unsigned cvtpk_bf16(float lo, float hi) {
    unsigned r;
    asm("v_cvt_pk_bf16_f32 %0, %1, %2" : "=v"(r) : "v"(lo), "v"(hi));
    return r;
}
__device__ __forceinline__ float exp2_fast(float x) {
    float r;
    asm("v_exp_f32 %0, %1" : "=v"(r) : "v"(x));
    return r;
}
__device__ __forceinline__ float rcp_fast(float x) {
    float r;
    asm("v_rcp_f32 %0, %1" : "=v"(r) : "v"(x));
    return r;
}

// ---------------------------------------------------------------- fused prologue
// Sections by block range (each = proven standalone kernel body):
//   [0, CF)        feat f32->bf16 cast          (3,145,728 f32x4 granules)
//   [CF, CF+CW)    w_qkv + w_proj cast          (184,320 granules)
//   [CF+CW, +8)    posmax partials              (8 blocks, plain stores -> no memset)
#define CF_BLK 12288
#define CW_BLK 720
#define WQN 110592   // 3*C*C/4 granules
#define WPN 73728    // C*2C/4 granules
__global__ __launch_bounds__(256) void prologue_kernel(const float* __restrict__ pos,
                                                       const float* __restrict__ feat,
                                                       const float* __restrict__ wq,
                                                       const float* __restrict__ wp,
                                                       unsigned* __restrict__ pmax,
                                                       ushort* __restrict__ featb,
                                                       ushort* __restrict__ wqb,
                                                       ushort* __restrict__ wpb) {
    const int bid = blockIdx.x;
    if (bid < CF_BLK) {
        int i = bid * 256 + threadIdx.x;                   // < 3,145,728 exactly
        float4 a = reinterpret_cast<const float4*>(feat)[i];
        unsigned u01 = cvtpk_bf16(a.x, a.y), u23 = cvtpk_bf16(a.z, a.w);
        ushort4 o = { (ushort)(u01 & 0xffff), (ushort)(u01 >> 16),
                      (ushort)(u23 & 0xffff), (ushort)(u23 >> 16) };
        reinterpret_cast<ushort4*>(featb)[i] = o;
        return;
    }
    if (bid < CF_BLK + CW_BLK) {
        int i = (bid - CF_BLK) * 256 + threadIdx.x;
        if (i >= WQN + WPN) return;
        const float* src; ushort* dst; int j;
        if (i < WQN) { src = wq; dst = wqb; j = i; }
        else         { src = wp; dst = wpb; j = i - WQN; }
        float4 a = reinterpret_cast<const float4*>(src)[j];
        unsigned u01 = cvtpk_bf16(a.x, a.y), u23 = cvtpk_bf16(a.z, a.w);
        ushort4 o = { (ushort)(u01 & 0xffff), (ushort)(u01 >> 16),
                      (ushort)(u23 & 0xffff), (ushort)(u23 >> 16) };
        reinterpret_cast<ushort4*>(dst)[j] = o;
        return;
    }
    // ---- posmax partials (8 virtual blocks; plain stores, rewritten every call)
    {
        int vb = bid - CF_BLK - CW_BLK;                    // 0..7
        int tid = vb * 256 + threadIdx.x;
        float m0 = 0.f, m1 = 0.f;
        for (int i = tid; i < BN_; i += 8 * 256) {
            m0 = fmaxf(m0, pos[(size_t)i * 2 + 0]);
            m1 = fmaxf(m1, pos[(size_t)i * 2 + 1]);
        }
        #pragma unroll
        for (int off = 32; off; off >>= 1) {
            m0 = fmaxf(m0, __shfl_down(m0, off));
            m1 = fmaxf(m1, __shfl_down(m1, off));
        }
        __shared__ float s0[4], s1[4];
        int w = threadIdx.x >> 6;
        if ((threadIdx.x & 63) == 0) { s0[w] = m0; s1[w] = m1; }
        __syncthreads();
        if (threadIdx.x == 0) {
            for (int i = 1; i < 4; i++) { m0 = fmaxf(m0, s0[i]); m1 = fmaxf(m1, s1[i]); }
            pmax[2 * vb + 0] = __float_as_uint(m0);
            pmax[2 * vb + 1] = __float_as_uint(m1);
        }
    }
}

// ---------------------------------------------------------------- QKV GEMM (256x128, single-buffer)
// r17-proven best (47.4us): 8 waves (4x2), BK=64, 6 K-steps; T2 swizzle + XCD
// row-strip remap. Direct slab scatter epilogue.
__global__ __launch_bounds__(512) void gemm_qkv_s(const ushort* __restrict__ A,
                                                  const ushort* __restrict__ Bw,
                                                  const float* __restrict__ bias,
                                                  ushort* __restrict__ qkv) {
    constexpr int NB = QKVD / 128;            // 9 column blocks
    __shared__ ushort As[256 * 64];           // 32 KB
    __shared__ ushort Bs[128 * 64];           // 16 KB
    const int wgid = blockIdx.x;              // 8*16*9 = 1152
    const int xcd  = wgid & 7;
    const int loc  = wgid >> 3;               // [0, 144)
    const int bm = (xcd * 16 + loc / NB) * 256;
    const int bn = (loc % NB) * 128;
    const int t = threadIdx.x;
    const int l = t & 63;
    const int wid = t >> 6;                   // 0..7
    const int wr = wid >> 1, wc = wid & 1;    // 4x2 wave grid, wave = 64x64 out
    const int fr = l & 15, fq = l >> 4;

    f32x4 zero = {0.f, 0.f, 0.f, 0.f};
    f32x4 acc[4][4];
    #pragma unroll
    for (int m = 0; m < 4; m++)
        #pragma unroll
        for (int n = 0; n < 4; n++) acc[m][n] = zero;

    for (int k0 = 0; k0 < 384; k0 += 64) {
        #pragma unroll
        for (int i = 0; i < 4; i++) {             // A: 256x64
            int elem = (i * 512 + t) * 8;
            int row = elem >> 6, kk = elem & 63;
            int kks = kk ^ ((row & 7) << 3);
            load_lds_16B(A + (size_t)(bm + row) * 384 + k0 + kks, &As[elem]);
        }
        #pragma unroll
        for (int i = 0; i < 2; i++) {             // B: 128x64
            int elem = (i * 512 + t) * 8;
            int row = elem >> 6, kk = elem & 63;
            int kks = kk ^ ((row & 7) << 3);
            load_lds_16B(Bw + (size_t)(bn + row) * 384 + k0 + kks, &Bs[elem]);
        }
        __syncthreads();
        #pragma unroll
        for (int kk = 0; kk < 64; kk += 32) {
            bf16x8 af[4], bfr[4];
            #pragma unroll
            for (int m = 0; m < 4; m++) {
                int row = wr * 64 + m * 16 + fr;
                af[m] = *reinterpret_cast<const bf16x8*>(&As[row * 64 + ((kk + fq * 8) ^ ((row & 7) << 3))]);
            }
            #pragma unroll
            for (int n = 0; n < 4; n++) {
                int row = wc * 64 + n * 16 + fr;
                bfr[n] = *reinterpret_cast<const bf16x8*>(&Bs[row * 64 + ((kk + fq * 8) ^ ((row & 7) << 3))]);
            }
            #pragma unroll
            for (int m = 0; m < 4; m++)
                #pragma unroll
                for (int n = 0; n < 4; n++)
                    acc[m][n] = __builtin_amdgcn_mfma_f32_16x16x32_bf16(af[m], bfr[n], acc[m][n], 0, 0, 0);
        }
        __syncthreads();
    }
    // epilogue -> qkv slab [bh][n][96]; 256-row tile all in one batch (8192 % 256 == 0)
    const int bq = bm >> 13;          // batch
    const int nbase = bm & (N_ - 1);  // row within batch
    #pragma unroll
    for (int n = 0; n < 4; n++) {
        int col = bn + wc * 64 + n * 16 + fr;
        int hc = col / 96, cn = col % 96;
        float bc = bias[col];
        ushort* base = qkv + ((size_t)(bq * H_ + hc) * N_ + nbase) * 96 + cn;
        #pragma unroll
        for (int m = 0; m < 4; m++) {
            #pragma unroll
            for (int r = 0; r < 4; r++) {
                int rowoff = wr * 64 + m * 16 + fq * 4 + r;
                unsigned up = cvtpk_bf16(acc[m][n][r] + bc, 0.f);
                base[(size_t)rowoff * 96] = (ushort)(up & 0xffff);
            }
        }
    }
}

// ---------------------------------------------------------------- MFMA attention (recompute-QK^T)
// 1-D grid: id%8 = bh&7 -> all 32 kc-blocks of one bh on one XCD (L2-resident slabs).
// 256 threads = 4 waves; wave w owns queries [64w, 64w+64) in TWO 32-query passes.
// Softmax via QK^T RECOMPUTE: pass A reduces each 32x32 score tile to the row max
// immediately (never held); pass B recomputes the tile (deterministic MFMA), applies
// bias/exp, converts to P-fragment, feeds PV at once. Peak live regs ~90 (no 128-f32
// sac hold -> no AGPR shuttle). kf is asm-laundered in pass B to block MFMA CSE.
// C/D layout (32x32): col = lane&31, row = (r&3) + 8*(r>>2) + 4*(lane>>5).
__global__ __launch_bounds__(256, 3) void attn_kernel(const ushort* __restrict__ qkv,
                                                      const int* __restrict__ member_idx,
                                                      const float* __restrict__ pos,
                                                      const float* __restrict__ w_pos,
                                                      const unsigned* __restrict__ pmax_u,
                                                      ushort* __restrict__ feat2) {
    const int id = blockIdx.x;
    const int bh = (id >> 8) * 8 + (id & 7);
    const int kc = (id >> 3) & 31;
    const int b = bh / H_, h = bh % H_;
    __shared__ ushort Ks[M_ * 16];        // 8 KB  [member][16]
    __shared__ ushort Vt[64 * VSTR];      // 32.5 KB [channel][member], padded stride
    __shared__ float  SpA[M_];            // bias*log2e, crow-reordered
    __shared__ int    Idx[M_];
    __shared__ float  dinvS[M_];          // per-query 1/sum

    const int t  = threadIdx.x;
    const int w  = t >> 6, l = t & 63;
    const int hi = l >> 5, ln = l & 31;
    const int* mi = member_idx + (((size_t)b * H_ + h) * K_ + kc) * M_;
    const ushort* slab = qkv + (size_t)bh * N_ * 96;
    const size_t rowbase = (size_t)b * N_;
    const float scale2 = 0.17677669529663687f * LOG2E;  // (C/H)^-0.5 * log2(e)

    // ---- early issue: Q fragments for both passes (queries 64w+ln, 64w+32+ln)
    const int nq0 = mi[w * 64 + ln];
    const int nq1 = mi[w * 64 + 32 + ln];
    bf16x8 qf0 = *(const bf16x8*)(slab + (size_t)nq0 * 96 + hi * 8);
    bf16x8 qf1 = *(const bf16x8*)(slab + (size_t)nq1 * 96 + hi * 8);
    // ---- K stage via global_load_lds (2 iters over 256 threads; r6-proven map)
    #pragma unroll
    for (int it = 0; it < 2; it++) {
        int idx = it * 256 + t;
        int row = idx >> 1, half = idx & 1;
        int n = mi[row];
        load_lds_16B(slab + (size_t)n * 96 + 16 + half * 8, &Ks[idx * 8]);
    }
    // ---- V load + pack-transpose via v_perm (r6 map: u = t>>1, 2 cq halves)
    {
        int u = t >> 1, cqh = t & 1;
        int n0 = mi[2 * u], n1 = mi[2 * u + 1];
        #pragma unroll
        for (int qq = 0; qq < 2; qq++) {
            int cq = 2 * cqh + qq;
            const ushort* s0 = slab + (size_t)n0 * 96 + 32 + cq * 16;
            const ushort* s1 = slab + (size_t)n1 * 96 + 32 + cq * 16;
            union { ushort8v v; unsigned u4[4]; } v0a, v0b, v1a, v1b;
            v0a.v = *(const ushort8v*)s0;
            v0b.v = *(const ushort8v*)(s0 + 8);
            v1a.v = *(const ushort8v*)s1;
            v1b.v = *(const ushort8v*)(s1 + 8);
            #pragma unroll
            for (int iw = 0; iw < 4; iw++) {
                unsigned ea = __builtin_amdgcn_perm(v1a.u4[iw], v0a.u4[iw], 0x05040100u);
                unsigned oa = __builtin_amdgcn_perm(v1a.u4[iw], v0a.u4[iw], 0x07060302u);
                *(unsigned*)&Vt[(cq * 16 + 2 * iw)     * VSTR + 2 * u] = ea;
                *(unsigned*)&Vt[(cq * 16 + 2 * iw + 1) * VSTR + 2 * u] = oa;
                unsigned eb = __builtin_amdgcn_perm(v1b.u4[iw], v0b.u4[iw], 0x05040100u);
                unsigned ob = __builtin_amdgcn_perm(v1b.u4[iw], v0b.u4[iw], 0x07060302u);
                *(unsigned*)&Vt[(cq * 16 + 8 + 2 * iw)     * VSTR + 2 * u] = eb;
                *(unsigned*)&Vt[(cq * 16 + 8 + 2 * iw + 1) * VSTR + 2 * u] = ob;
            }
        }
    }
    // ---- bias + Idx (crow-reordered, r13-proven formula; pmax = max of 8 partials)
    {
        int n = mi[t];
        Idx[t] = n;
        float f0 = __uint_as_float(pmax_u[0]), f1 = __uint_as_float(pmax_u[1]);
        #pragma unroll
        for (int k = 1; k < 8; k++) {
            f0 = fmaxf(f0, __uint_as_float(pmax_u[2 * k + 0]));
            f1 = fmaxf(f1, __uint_as_float(pmax_u[2 * k + 1]));
        }
        float inv0 = rcp_fast(f0);
        float inv1 = rcp_fast(f1);
        float sp = pos[(rowbase + n) * 2 + 0] * inv0 * w_pos[h * 2 + 0]
                 + pos[(rowbase + n) * 2 + 1] * inv1 * w_pos[h * 2 + 1];
        int jj = t & 31, jt = t >> 5;
        int r  = (jj & 3) | ((jj >> 3) << 2);
        int hb = (jj >> 2) & 1;
        SpA[jt * 32 + hb * 16 + r] = sp * LOG2E;
    }
    __syncthreads();

    f32x16 zero16;
    #pragma unroll
    for (int i = 0; i < 16; i++) zero16[i] = 0.f;
    ushort* f2slab = feat2 + (size_t)bh * N_ * 64;

    #pragma unroll
    for (int p = 0; p < 2; p++) {
        const int qb = w * 64 + p * 32;
        const bf16x8 qf = p ? qf1 : qf0;

        // ---- pass A: row max (each score tile reduced immediately, never held)
        float mx = -3.0e38f;
        #pragma unroll
        for (int jt = 0; jt < 8; jt++) {
            bf16x8 kf = *(const bf16x8*)&Ks[(32 * jt + ln) * 16 + hi * 8];
            f32x16 s = __builtin_amdgcn_mfma_f32_32x32x16_bf16(kf, qf, zero16, 0, 0, 0);
            f32x4 bia[4];
            #pragma unroll
            for (int q4 = 0; q4 < 4; q4++)
                bia[q4] = *(const f32x4*)&SpA[jt * 32 + hi * 16 + q4 * 4];
            #pragma unroll
            for (int r = 0; r < 16; r++)
                s[r] = fmaf(s[r], scale2, bia[r >> 2][r & 3]);
            #pragma unroll
            for (int r = 0; r < 16; r += 2)
                mx = fmaxf(mx, fmaxf(s[r], s[r + 1]));   // -> v_max3
        }
        mx = fmaxf(mx, __shfl_xor(mx, 32));

        // ---- pass B: recompute tile -> exp -> P-frag -> PV (nothing held across tiles)
        float sum = 0.f;
        f32x16 oa0 = zero16, oa1 = zero16;
        #pragma unroll
        for (int jt = 0; jt < 8; jt++) {
            bf16x8 kf = *(const bf16x8*)&Ks[(32 * jt + ln) * 16 + hi * 8];
            asm volatile("" : "+v"(kf));   // block CSE with pass A's identical MFMA
            f32x16 s = __builtin_amdgcn_mfma_f32_32x32x16_bf16(kf, qf, zero16, 0, 0, 0);
            f32x4 bia[4];
            #pragma unroll
            for (int q4 = 0; q4 < 4; q4++)
                bia[q4] = *(const f32x4*)&SpA[jt * 32 + hi * 16 + q4 * 4];
            #pragma unroll
            for (int r = 0; r < 16; r++) {
                float pv = exp2_fast(fmaf(s[r], scale2, bia[r >> 2][r & 3]) - mx);
                s[r] = pv;
                sum += pv;
            }
            __builtin_amdgcn_s_setprio(1);
            #pragma unroll
            for (int half = 0; half < 2; half++) {
                const int hf = half * 8;
                unsigned a0 = cvtpk_bf16(s[hf + 0], s[hf + 1]);
                unsigned a1 = cvtpk_bf16(s[hf + 2], s[hf + 3]);
                unsigned b0 = cvtpk_bf16(s[hf + 4], s[hf + 5]);
                unsigned b1 = cvtpk_bf16(s[hf + 6], s[hf + 7]);
                asm("v_permlane32_swap_b32 %0, %1" : "+v"(a0), "+v"(b0));
                asm("v_permlane32_swap_b32 %0, %1" : "+v"(a1), "+v"(b1));
                union { unsigned uu[4]; bf16x8 v; } pa;
                pa.uu[0] = a0; pa.uu[1] = a1; pa.uu[2] = b0; pa.uu[3] = b1;
                const int mo = (jt * 2 + half) * 16 + hi * 8;
                union { ushort4v hv[2]; bf16x8 v; } vf0, vf1;
                vf0.hv[0] = *(const ushort4v*)&Vt[ln * VSTR + mo];
                vf0.hv[1] = *(const ushort4v*)&Vt[ln * VSTR + mo + 4];
                vf1.hv[0] = *(const ushort4v*)&Vt[(ln + 32) * VSTR + mo];
                vf1.hv[1] = *(const ushort4v*)&Vt[(ln + 32) * VSTR + mo + 4];
                oa0 = __builtin_amdgcn_mfma_f32_32x32x16_bf16(pa.v, vf0.v, oa0, 0, 0, 0);
                oa1 = __builtin_amdgcn_mfma_f32_32x32x16_bf16(pa.v, vf1.v, oa1, 0, 0, 0);
            }
            __builtin_amdgcn_s_setprio(0);
        }
        sum += __shfl_xor(sum, 32);
        float inv = rcp_fast(sum);
        if (hi == 0) dinvS[qb + ln] = inv;

        // ---- epilogue (r13 body): lane holds O[i=crow(r,hi)][c=ln(+32)]
        #pragma unroll
        for (int r = 0; r < 16; r++) {
            int crow = (r & 3) + 8 * (r >> 2) + 4 * hi;
            float dv = dinvS[qb + crow];
            int ni = Idx[qb + crow];
            unsigned up = cvtpk_bf16(oa0[r] * dv, oa1[r] * dv);
            ushort* dst = f2slab + (size_t)ni * 64 + ln;
            dst[0]  = (ushort)(up & 0xffff);
            dst[32] = (ushort)(up >> 16);
        }
    }
}

// ---------------------------------------------------------------- proj GEMM (256x128, single-buffer)
// r20-proven structure.
__global__ __launch_bounds__(512) void gemm_proj_s(const ushort* __restrict__ A,
                                                   const ushort* __restrict__ Bw,
                                                   const float* __restrict__ bias,
                                                   float* __restrict__ Cout) {
    constexpr int NB = C_ / 128;              // 3 column blocks
    __shared__ ushort As[256 * 64];           // 32 KB
    __shared__ ushort Bs[128 * 64];           // 16 KB
    const int wgid = blockIdx.x;              // 8*16*3 = 384
    const int xcd  = wgid & 7;
    const int loc  = wgid >> 3;               // [0, 48)
    const int bm = (xcd * 16 + loc / NB) * 256;
    const int bn = (loc % NB) * 128;
    const int t = threadIdx.x;
    const int l = t & 63;
    const int wid = t >> 6;
    const int wr = wid >> 1, wc = wid & 1;    // 4x2 wave grid
    const int fr = l & 15, fq = l >> 4;
    const int bq = bm >> 13;                  // batch
    const int nbase = bm & (N_ - 1);

    f32x4 zero = {0.f, 0.f, 0.f, 0.f};
    f32x4 acc[4][4];
    #pragma unroll
    for (int m = 0; m < 4; m++)
        #pragma unroll
        for (int n = 0; n < 4; n++) acc[m][n] = zero;

    for (int k0 = 0; k0 < 768; k0 += 64) {
        const ushort* Aslab = A + ((size_t)(bq * H_ + (k0 >> 6)) * N_ + nbase) * 64;
        #pragma unroll
        for (int i = 0; i < 4; i++) {             // A: 256x64
            int elem = (i * 512 + t) * 8;
            int row = elem >> 6, kk = elem & 63;
            int kks = kk ^ ((row & 7) << 3);
            load_lds_16B(Aslab + (size_t)row * 64 + kks, &As[elem]);
        }
        #pragma unroll
        for (int i = 0; i < 2; i++) {             // B: 128x64
            int elem = (i * 512 + t) * 8;
            int row = elem >> 6, kk = elem & 63;
            int kks = kk ^ ((row & 7) << 3);
            load_lds_16B(Bw + (size_t)(bn + row) * 768 + k0 + kks, &Bs[elem]);
        }
        __syncthreads();
        #pragma unroll
        for (int kk = 0; kk < 64; kk += 32) {
            bf16x8 af[4], bfr[4];
            #pragma unroll
            for (int m = 0; m < 4; m++) {
                int row = wr * 64 + m * 16 + fr;
                af[m] = *reinterpret_cast<const bf16x8*>(&As[row * 64 + ((kk + fq * 8) ^ ((row & 7) << 3))]);
            }
            #pragma unroll
            for (int n = 0; n < 4; n++) {
                int row = wc * 64 + n * 16 + fr;
                bfr[n] = *reinterpret_cast<const bf16x8*>(&Bs[row * 64 + ((kk + fq * 8) ^ ((row & 7) << 3))]);
            }
            #pragma unroll
            for (int m = 0; m < 4; m++)
                #pragma unroll
                for (int n = 0; n < 4; n++)
                    acc[m][n] = __builtin_amdgcn_mfma_f32_16x16x32_bf16(af[m], bfr[n], acc[m][n], 0, 0, 0);
        }
        __syncthreads();
    }
    #pragma unroll
    for (int n = 0; n < 4; n++) {
        int col = bn + wc * 64 + n * 16 + fr;
        float bc = bias[col];
        #pragma unroll
        for (int m = 0; m < 4; m++) {
            #pragma unroll
            for (int r = 0; r < 4; r++) {
                size_t row = bm + wr * 64 + m * 16 + fq * 4 + r;
                Cout[row * C_ + col] = acc[m][n][r] + bc;
            }
        }
    }
}

// ---------------------------------------------------------------- launch
extern "C" void kernel_launch(void* const* d_in, const int* in_sizes, int n_in,
                              void* d_out, int out_size, void* d_ws, size_t ws_size,
                              hipStream_t stream) {
    const float* pos    = (const float*)d_in[0];
    const float* feat   = (const float*)d_in[1];
    const int*   midx   = (const int*)  d_in[2];
    const float* w_qkv  = (const float*)d_in[3];
    const float* b_qkv  = (const float*)d_in[4];
    const float* w_pos  = (const float*)d_in[5];
    const float* b_pos  = (const float*)d_in[6];  (void)b_pos; // cancels in softmax
    const float* w_proj = (const float*)d_in[7];
    const float* b_proj = (const float*)d_in[8];
    float* out = (float*)d_out;

    // workspace (126.4 MB, r5-proven):
    // [pmax 16 slots | qkv 75.5MB | wproj 0.59MB | REGION: {featb 25.2 + wqkvb 0.88} -> feat2 50.3]
    char* ws = (char*)d_ws;
    unsigned* pmax  = (unsigned*)ws;
    ushort*   qkv   = (ushort*)(ws + 256);
    ushort*   wproj = (ushort*)(ws + 256 + 75497472);
    char*     region = ws + 256 + 75497472 + 589824;
    ushort*   featb = (ushort*)region;
    ushort*   wqkvb = (ushort*)(region + 25165824);
    ushort*   feat2 = (ushort*)region;   // overwrites featb/wqkvb after gemm_qkv_s

    // no memset: posmax partials are plain-stored (fully rewritten) every call
    prologue_kernel<<<CF_BLK + CW_BLK + 8, 256, 0, stream>>>(pos, feat, w_qkv, w_proj,
                                                             pmax, featb, wqkvb, wproj);
    gemm_qkv_s<<<8 * 16 * (QKVD / 128), 512, 0, stream>>>(featb, wqkvb, b_qkv, qkv);
    attn_kernel<<<6 * 256, 256, 0, stream>>>(qkv, midx, pos, w_pos, pmax, feat2);
    gemm_proj_s<<<8 * 16 * (C_ / 128), 512, 0, stream>>>(feat2, wproj, b_proj, out);
}